// Round 1
// baseline (7484.485 us; speedup 1.0000x reference)
//
#include <hip/hip_runtime.h>

#define NFEAT_IN 21
#define NHID 16
#define NOUT 6

__global__ void k_init_deg(float* __restrict__ deg, int n) {
    int i = blockIdx.x * blockDim.x + threadIdx.x;
    if (i < n) deg[i] = 1.0f;  // self-loop
}

__global__ void k_count_deg(const int* __restrict__ dst, float* __restrict__ deg, int ne) {
    int e = blockIdx.x * blockDim.x + threadIdx.x;
    if (e < ne) atomicAdd(deg + dst[e], 1.0f);
}

__global__ void k_dinv(float* __restrict__ deg, int n) {
    int i = blockIdx.x * blockDim.x + threadIdx.x;
    if (i < n) deg[i] = rsqrtf(deg[i]);  // deg >= 1 always (self-loop)
}

// h = x @ W1, scaled by dinv[i]; write to hs1 and init agg1 with it (self-loop term)
__global__ void k_dense1(const float* __restrict__ x, const float* __restrict__ W1,
                         const float* __restrict__ dinv, float* __restrict__ hs1,
                         float* __restrict__ agg1, int n) {
    __shared__ float sW[NFEAT_IN * NHID];
    for (int t = threadIdx.x; t < NFEAT_IN * NHID; t += blockDim.x) sW[t] = W1[t];
    __syncthreads();
    int i = blockIdx.x * blockDim.x + threadIdx.x;
    if (i >= n) return;
    float xi[NFEAT_IN];
#pragma unroll
    for (int k = 0; k < NFEAT_IN; k++) xi[k] = x[(size_t)i * NFEAT_IN + k];
    float di = dinv[i];
#pragma unroll
    for (int j = 0; j < NHID; j++) {
        float acc = 0.f;
#pragma unroll
        for (int k = 0; k < NFEAT_IN; k++) acc += xi[k] * sW[k * NHID + j];
        acc *= di;
        hs1[(size_t)i * NHID + j] = acc;
        agg1[(size_t)i * NHID + j] = acc;
    }
}

__global__ void k_scatter1(const int* __restrict__ src, const int* __restrict__ dst,
                           const float* __restrict__ hs1, float* __restrict__ agg1, int ne) {
    int e = blockIdx.x * blockDim.x + threadIdx.x;
    if (e >= ne) return;
    int s = src[e], d = dst[e];
    const float4* hp = (const float4*)(hs1 + (size_t)s * NHID);
    float* ap = agg1 + (size_t)d * NHID;
#pragma unroll
    for (int q = 0; q < 4; q++) {
        float4 v = hp[q];
        atomicAdd(ap + 4 * q + 0, v.x);
        atomicAdd(ap + 4 * q + 1, v.y);
        atomicAdd(ap + 4 * q + 2, v.z);
        atomicAdd(ap + 4 * q + 3, v.w);
    }
}

// z = relu(agg1*dinv + b1); hs2 = (z @ W2) * dinv; agg2 = hs2 (self-loop init)
__global__ void k_fin1_dense2(const float* __restrict__ agg1, const float* __restrict__ b1,
                              const float* __restrict__ W2, const float* __restrict__ dinv,
                              float* __restrict__ hs2, float* __restrict__ agg2, int n) {
    __shared__ float sW[NHID * NOUT];
    __shared__ float sb[NHID];
    for (int t = threadIdx.x; t < NHID * NOUT; t += blockDim.x) sW[t] = W2[t];
    for (int t = threadIdx.x; t < NHID; t += blockDim.x) sb[t] = b1[t];
    __syncthreads();
    int i = blockIdx.x * blockDim.x + threadIdx.x;
    if (i >= n) return;
    float di = dinv[i];
    float z[NHID];
#pragma unroll
    for (int j = 0; j < NHID; j++)
        z[j] = fmaxf(agg1[(size_t)i * NHID + j] * di + sb[j], 0.0f);
#pragma unroll
    for (int k = 0; k < NOUT; k++) {
        float acc = 0.f;
#pragma unroll
        for (int j = 0; j < NHID; j++) acc += z[j] * sW[j * NOUT + k];
        acc *= di;
        hs2[(size_t)i * NOUT + k] = acc;
        agg2[(size_t)i * NOUT + k] = acc;
    }
}

__global__ void k_scatter2(const int* __restrict__ src, const int* __restrict__ dst,
                           const float* __restrict__ hs2, float* __restrict__ agg2, int ne) {
    int e = blockIdx.x * blockDim.x + threadIdx.x;
    if (e >= ne) return;
    int s = src[e], d = dst[e];
    const float* hp = hs2 + (size_t)s * NOUT;
    float* ap = agg2 + (size_t)d * NOUT;
#pragma unroll
    for (int k = 0; k < NOUT; k++) atomicAdd(ap + k, hp[k]);
}

__global__ void k_fin2(const float* __restrict__ agg2, const float* __restrict__ b2,
                       const float* __restrict__ dinv, float* __restrict__ out, int n) {
    __shared__ float sb[NOUT];
    for (int t = threadIdx.x; t < NOUT; t += blockDim.x) sb[t] = b2[t];
    __syncthreads();
    int i = blockIdx.x * blockDim.x + threadIdx.x;
    if (i >= n) return;
    float di = dinv[i];
    float v[NOUT];
    float m = -1e30f;
#pragma unroll
    for (int k = 0; k < NOUT; k++) {
        v[k] = agg2[(size_t)i * NOUT + k] * di + sb[k];
        m = fmaxf(m, v[k]);
    }
    float s = 0.f;
#pragma unroll
    for (int k = 0; k < NOUT; k++) s += expf(v[k] - m);
    float l = logf(s);
#pragma unroll
    for (int k = 0; k < NOUT; k++) out[(size_t)i * NOUT + k] = v[k] - m - l;
}

extern "C" void kernel_launch(void* const* d_in, const int* in_sizes, int n_in,
                              void* d_out, int out_size, void* d_ws, size_t ws_size,
                              hipStream_t stream) {
    const float* x  = (const float*)d_in[0];
    const int*   ei = (const int*)d_in[1];
    const float* W1 = (const float*)d_in[2];
    const float* b1 = (const float*)d_in[3];
    const float* W2 = (const float*)d_in[4];
    const float* b2 = (const float*)d_in[5];
    float* out = (float*)d_out;

    int n  = in_sizes[0] / NFEAT_IN;   // 200000 nodes
    int ne = in_sizes[1] / 2;          // 6400000 edges
    const int* src = ei;
    const int* dst = ei + ne;

    float* ws   = (float*)d_ws;
    float* dinv = ws;                          // n
    float* hs1  = dinv + n;                    // n*16
    float* agg1 = hs1 + (size_t)n * NHID;      // n*16
    float* hs2  = agg1 + (size_t)n * NHID;     // n*6
    float* agg2 = hs2 + (size_t)n * NOUT;      // n*6

    const int B = 256;
    int gn = (n + B - 1) / B;
    int ge = (ne + B - 1) / B;

    k_init_deg<<<gn, B, 0, stream>>>(dinv, n);
    k_count_deg<<<ge, B, 0, stream>>>(dst, dinv, ne);
    k_dinv<<<gn, B, 0, stream>>>(dinv, n);
    k_dense1<<<gn, B, 0, stream>>>(x, W1, dinv, hs1, agg1, n);
    k_scatter1<<<ge, B, 0, stream>>>(src, dst, hs1, agg1, ne);
    k_fin1_dense2<<<gn, B, 0, stream>>>(agg1, b1, W2, dinv, hs2, agg2, n);
    k_scatter2<<<ge, B, 0, stream>>>(src, dst, hs2, agg2, ne);
    k_fin2<<<gn, B, 0, stream>>>(agg2, b2, dinv, out, n);
}

// Round 2
// 1275.164 us; speedup vs baseline: 5.8694x; 5.8694x over previous
//
#include <hip/hip_runtime.h>

#define NFEAT_IN 21
#define NHID 16
#define NOUT 6
#define SCAN_B 256   // elems per block in node-scan

__global__ void k_zero_deg(int* __restrict__ deg, int n) {
    int i = blockIdx.x * blockDim.x + threadIdx.x;
    if (i < n) deg[i] = 0;
}

__global__ void k_count_deg(const int* __restrict__ dst, int* __restrict__ deg, int ne) {
    int e = blockIdx.x * blockDim.x + threadIdx.x;
    if (e < ne) atomicAdd(deg + dst[e], 1);
}

__global__ void k_dinv(const int* __restrict__ deg, float* __restrict__ dinv, int n) {
    int i = blockIdx.x * blockDim.x + threadIdx.x;
    if (i < n) dinv[i] = rsqrtf((float)deg[i] + 1.0f);  // +1 self-loop
}

// ---- exclusive prefix sum over deg -> rowptr (3 kernels) ----
__global__ void k_block_sum(const int* __restrict__ deg, int* __restrict__ bsum, int n) {
    __shared__ int s[SCAN_B];
    int t = threadIdx.x;
    int i = blockIdx.x * SCAN_B + t;
    s[t] = (i < n) ? deg[i] : 0;
    __syncthreads();
    for (int off = SCAN_B / 2; off > 0; off >>= 1) {
        if (t < off) s[t] += s[t + off];
        __syncthreads();
    }
    if (t == 0) bsum[blockIdx.x] = s[0];
}

__global__ void k_scan_partials(const int* __restrict__ bsum, int* __restrict__ boff, int nb) {
    __shared__ int s[1024];
    int t = threadIdx.x;
    int v = (t < nb) ? bsum[t] : 0;
    s[t] = v;
    __syncthreads();
    for (int off = 1; off < 1024; off <<= 1) {
        int tv = (t >= off) ? s[t - off] : 0;
        __syncthreads();
        s[t] += tv;
        __syncthreads();
    }
    boff[t] = s[t] - v;  // exclusive
}

__global__ void k_scan_final(const int* __restrict__ deg, const int* __restrict__ boff,
                             int* __restrict__ rowptr, int* __restrict__ cursor, int n) {
    __shared__ int s[SCAN_B];
    int t = threadIdx.x;
    int i = blockIdx.x * SCAN_B + t;
    int v = (i < n) ? deg[i] : 0;
    s[t] = v;
    __syncthreads();
    for (int off = 1; off < SCAN_B; off <<= 1) {
        int tv = (t >= off) ? s[t - off] : 0;
        __syncthreads();
        s[t] += tv;
        __syncthreads();
    }
    if (i < n) {
        int start = boff[blockIdx.x] + s[t] - v;
        rowptr[i] = start;
        cursor[i] = start;
    }
}

__global__ void k_fill_csr(const int* __restrict__ src, const int* __restrict__ dst,
                           int* __restrict__ cursor, int* __restrict__ csr, int ne) {
    int e = blockIdx.x * blockDim.x + threadIdx.x;
    if (e >= ne) return;
    int pos = atomicAdd(cursor + dst[e], 1);
    csr[pos] = src[e];
}

// hs1 = (x @ W1) * dinv[i]
__global__ void k_dense1(const float* __restrict__ x, const float* __restrict__ W1,
                         const float* __restrict__ dinv, float* __restrict__ hs1, int n) {
    __shared__ float sW[NFEAT_IN * NHID];
    for (int t = threadIdx.x; t < NFEAT_IN * NHID; t += blockDim.x) sW[t] = W1[t];
    __syncthreads();
    int i = blockIdx.x * blockDim.x + threadIdx.x;
    if (i >= n) return;
    float xi[NFEAT_IN];
#pragma unroll
    for (int k = 0; k < NFEAT_IN; k++) xi[k] = x[(size_t)i * NFEAT_IN + k];
    float di = dinv[i];
#pragma unroll
    for (int j = 0; j < NHID; j++) {
        float acc = 0.f;
#pragma unroll
        for (int k = 0; k < NFEAT_IN; k++) acc += xi[k] * sW[k * NHID + j];
        hs1[(size_t)i * NHID + j] = acc * di;
    }
}

// pull-aggregate layer1 + relu + dense2, fused. cursor[i] == end-of-row after fill.
__global__ void k_agg1_dense2(const int* __restrict__ rowptr, const int* __restrict__ cursor,
                              const int* __restrict__ csr, const float* __restrict__ hs1,
                              const float* __restrict__ b1, const float* __restrict__ W2,
                              const float* __restrict__ dinv, float* __restrict__ hs2, int n) {
    __shared__ float sW[NHID * NOUT];
    __shared__ float sb[NHID];
    for (int t = threadIdx.x; t < NHID * NOUT; t += blockDim.x) sW[t] = W2[t];
    for (int t = threadIdx.x; t < NHID; t += blockDim.x) sb[t] = b1[t];
    __syncthreads();
    int i = blockIdx.x * blockDim.x + threadIdx.x;
    if (i >= n) return;
    float acc[NHID];
    const float4* self = (const float4*)(hs1 + (size_t)i * NHID);
#pragma unroll
    for (int q = 0; q < 4; q++) {
        float4 v = self[q];
        acc[4 * q + 0] = v.x; acc[4 * q + 1] = v.y;
        acc[4 * q + 2] = v.z; acc[4 * q + 3] = v.w;
    }
    int e0 = rowptr[i], e1 = cursor[i];
    for (int j = e0; j < e1; j++) {
        int s = csr[j];
        const float4* hp = (const float4*)(hs1 + (size_t)s * NHID);
#pragma unroll
        for (int q = 0; q < 4; q++) {
            float4 v = hp[q];
            acc[4 * q + 0] += v.x; acc[4 * q + 1] += v.y;
            acc[4 * q + 2] += v.z; acc[4 * q + 3] += v.w;
        }
    }
    float di = dinv[i];
    float z[NHID];
#pragma unroll
    for (int j = 0; j < NHID; j++) z[j] = fmaxf(acc[j] * di + sb[j], 0.0f);
#pragma unroll
    for (int k = 0; k < NOUT; k++) {
        float h = 0.f;
#pragma unroll
        for (int j = 0; j < NHID; j++) h += z[j] * sW[j * NOUT + k];
        hs2[(size_t)i * NOUT + k] = h * di;
    }
}

// pull-aggregate layer2 + bias + log_softmax, fused.
__global__ void k_agg2(const int* __restrict__ rowptr, const int* __restrict__ cursor,
                       const int* __restrict__ csr, const float* __restrict__ hs2,
                       const float* __restrict__ b2, const float* __restrict__ dinv,
                       float* __restrict__ out, int n) {
    __shared__ float sb[NOUT];
    for (int t = threadIdx.x; t < NOUT; t += blockDim.x) sb[t] = b2[t];
    __syncthreads();
    int i = blockIdx.x * blockDim.x + threadIdx.x;
    if (i >= n) return;
    float acc[NOUT];
    {
        const float2* self = (const float2*)(hs2 + (size_t)i * NOUT);
#pragma unroll
        for (int q = 0; q < 3; q++) {
            float2 v = self[q];
            acc[2 * q + 0] = v.x; acc[2 * q + 1] = v.y;
        }
    }
    int e0 = rowptr[i], e1 = cursor[i];
    for (int j = e0; j < e1; j++) {
        int s = csr[j];
        const float2* hp = (const float2*)(hs2 + (size_t)s * NOUT);
#pragma unroll
        for (int q = 0; q < 3; q++) {
            float2 v = hp[q];
            acc[2 * q + 0] += v.x; acc[2 * q + 1] += v.y;
        }
    }
    float di = dinv[i];
    float v[NOUT];
    float m = -1e30f;
#pragma unroll
    for (int k = 0; k < NOUT; k++) {
        v[k] = acc[k] * di + sb[k];
        m = fmaxf(m, v[k]);
    }
    float s = 0.f;
#pragma unroll
    for (int k = 0; k < NOUT; k++) s += expf(v[k] - m);
    float l = logf(s);
#pragma unroll
    for (int k = 0; k < NOUT; k++) out[(size_t)i * NOUT + k] = v[k] - m - l;
}

extern "C" void kernel_launch(void* const* d_in, const int* in_sizes, int n_in,
                              void* d_out, int out_size, void* d_ws, size_t ws_size,
                              hipStream_t stream) {
    const float* x  = (const float*)d_in[0];
    const int*   ei = (const int*)d_in[1];
    const float* W1 = (const float*)d_in[2];
    const float* b1 = (const float*)d_in[3];
    const float* W2 = (const float*)d_in[4];
    const float* b2 = (const float*)d_in[5];
    float* out = (float*)d_out;

    int n  = in_sizes[0] / NFEAT_IN;   // 200000
    int ne = in_sizes[1] / 2;          // 6400000
    const int* src = ei;
    const int* dst = ei + ne;

    // workspace layout (64B-aligned chunks)
    char* base = (char*)d_ws;
    size_t off = 0;
    auto alloc = [&](size_t bytes) {
        void* p = base + off;
        off += (bytes + 63) & ~(size_t)63;
        return p;
    };
    int*   deg    = (int*)alloc((size_t)n * 4);
    int*   rowptr = (int*)alloc((size_t)n * 4);
    int*   cursor = (int*)alloc((size_t)n * 4);
    int*   bsum   = (int*)alloc(1024 * 4);
    int*   boff   = (int*)alloc(1024 * 4);
    int*   csr    = (int*)alloc((size_t)ne * 4);
    float* dinv   = (float*)alloc((size_t)n * 4);
    float* hs1    = (float*)alloc((size_t)n * NHID * 4);
    float* hs2    = (float*)alloc((size_t)n * NOUT * 4);

    const int B = 256;
    int gn = (n + B - 1) / B;
    int ge = (ne + B - 1) / B;
    int nb = (n + SCAN_B - 1) / SCAN_B;  // 782 <= 1024

    k_zero_deg<<<gn, B, 0, stream>>>(deg, n);
    k_count_deg<<<ge, B, 0, stream>>>(dst, deg, ne);
    k_dinv<<<gn, B, 0, stream>>>(deg, dinv, n);
    k_block_sum<<<nb, SCAN_B, 0, stream>>>(deg, bsum, n);
    k_scan_partials<<<1, 1024, 0, stream>>>(bsum, boff, nb);
    k_scan_final<<<nb, SCAN_B, 0, stream>>>(deg, boff, rowptr, cursor, n);
    k_fill_csr<<<ge, B, 0, stream>>>(src, dst, cursor, csr, ne);
    k_dense1<<<gn, B, 0, stream>>>(x, W1, dinv, hs1, n);
    k_agg1_dense2<<<gn, B, 0, stream>>>(rowptr, cursor, csr, hs1, b1, W2, dinv, hs2, n);
    k_agg2<<<gn, B, 0, stream>>>(rowptr, cursor, csr, hs2, b2, dinv, out, n);
}

// Round 3
// 1196.458 us; speedup vs baseline: 6.2555x; 1.0658x over previous
//
#include <hip/hip_runtime.h>

#define NFEAT_IN 21
#define NHID 16
#define NOUT 6
#define BSHIFT 8
#define BW (1 << BSHIFT)     // 256 nodes per bucket
#define NBMAX 1024           // supports n <= 262144
#define EPT 32
#define PB 256
#define CHUNK (PB * EPT)     // 8192 edges per partition block

__global__ void k_zero(int* __restrict__ p, int n) {
    int i = blockIdx.x * blockDim.x + threadIdx.x;
    if (i < n) p[i] = 0;
}

__global__ void k_hist(const int* __restrict__ dst, int* __restrict__ bcnt, int ne) {
    __shared__ int lcnt[NBMAX];
    for (int t = threadIdx.x; t < NBMAX; t += blockDim.x) lcnt[t] = 0;
    __syncthreads();
    int stride = gridDim.x * blockDim.x;
    for (int e = blockIdx.x * blockDim.x + threadIdx.x; e < ne; e += stride)
        atomicAdd(&lcnt[dst[e] >> BSHIFT], 1);
    __syncthreads();
    for (int t = threadIdx.x; t < NBMAX; t += blockDim.x)
        if (lcnt[t]) atomicAdd(&bcnt[t], lcnt[t]);
}

__global__ void k_scan(const int* __restrict__ bcnt, int* __restrict__ boff,
                       int* __restrict__ bcur) {
    __shared__ int s[NBMAX];
    int t = threadIdx.x;
    int v = bcnt[t];
    s[t] = v;
    __syncthreads();
    for (int off = 1; off < NBMAX; off <<= 1) {
        int tv = (t >= off) ? s[t - off] : 0;
        __syncthreads();
        s[t] += tv;
        __syncthreads();
    }
    int ex = s[t] - v;
    boff[t] = ex;
    bcur[t] = ex;
}

__global__ void k_partition(const int* __restrict__ src, const int* __restrict__ dst,
                            int* __restrict__ bcur, unsigned int* __restrict__ bucketed,
                            int ne) {
    __shared__ unsigned int ebd[CHUNK];   // (bucket<<16)|dst_local per staged edge
    __shared__ int lcnt[NBMAX];
    __shared__ int lbase[NBMAX];
    __shared__ int lcur[NBMAX];
    int t = threadIdx.x;
    long base = (long)blockIdx.x * CHUNK;
    for (int b = t; b < NBMAX; b += PB) lcnt[b] = 0;
    __syncthreads();
#pragma unroll
    for (int k = 0; k < EPT; k++) {
        int idx = t + k * PB;
        long e = base + idx;
        unsigned int v = 0xFFFF0000u;
        if (e < ne) {
            int d = dst[e];
            int b = d >> BSHIFT;
            v = ((unsigned int)b << 16) | (unsigned int)(d & (BW - 1));
            atomicAdd(&lcnt[b], 1);
        }
        ebd[idx] = v;
    }
    __syncthreads();
    for (int b = t; b < NBMAX; b += PB) {
        int c = lcnt[b];
        if (c > 0) lbase[b] = atomicAdd(&bcur[b], c);
        lcur[b] = 0;
    }
    __syncthreads();
#pragma unroll
    for (int k = 0; k < EPT; k++) {
        int idx = t + k * PB;
        unsigned int v = ebd[idx];
        unsigned int b = v >> 16;
        if (b == 0xFFFFu) continue;
        int r = atomicAdd(&lcur[b], 1);
        int s = src[base + idx];
        bucketed[lbase[b] + r] = ((unsigned int)s << BSHIFT) | (v & (BW - 1));
    }
}

__global__ void k_bucket_dinv(const unsigned int* __restrict__ bucketed,
                              const int* __restrict__ boff, const int* __restrict__ bcnt,
                              float* __restrict__ dinv, int n) {
    __shared__ int deg[BW];
    int b = blockIdx.x, t = threadIdx.x;
    deg[t] = 0;
    __syncthreads();
    int s0 = boff[b], c = bcnt[b];
    for (int j = t; j < c; j += BW) atomicAdd(&deg[bucketed[s0 + j] & (BW - 1)], 1);
    __syncthreads();
    int node = (b << BSHIFT) + t;
    if (node < n) dinv[node] = rsqrtf((float)deg[t] + 1.0f);
}

// hs1 = (x @ W1) * dinv[i]
__global__ void k_dense1(const float* __restrict__ x, const float* __restrict__ W1,
                         const float* __restrict__ dinv, float* __restrict__ hs1, int n) {
    __shared__ float sW[NFEAT_IN * NHID];
    for (int t = threadIdx.x; t < NFEAT_IN * NHID; t += blockDim.x) sW[t] = W1[t];
    __syncthreads();
    int i = blockIdx.x * blockDim.x + threadIdx.x;
    if (i >= n) return;
    float xi[NFEAT_IN];
#pragma unroll
    for (int k = 0; k < NFEAT_IN; k++) xi[k] = x[(size_t)i * NFEAT_IN + k];
    float di = dinv[i];
#pragma unroll
    for (int j = 0; j < NHID; j++) {
        float acc = 0.f;
#pragma unroll
        for (int k = 0; k < NFEAT_IN; k++) acc += xi[k] * sW[k * NHID + j];
        hs1[(size_t)i * NHID + j] = acc * di;
    }
}

// bucket-centric aggregate layer1 (LDS atomics) + relu + dense2; hs2 padded to 8 floats/node
__global__ void k_agg1(const unsigned int* __restrict__ bucketed, const int* __restrict__ boff,
                       const int* __restrict__ bcnt, const float* __restrict__ hs1,
                       const float* __restrict__ b1, const float* __restrict__ W2,
                       const float* __restrict__ dinv, float* __restrict__ hs2, int n) {
    __shared__ float acc[BW][NHID + 1];   // stride 17 -> conflict-free banks
    __shared__ float sW[NHID * NOUT];
    __shared__ float sb[NHID];
    int b = blockIdx.x, t = threadIdx.x;
#pragma unroll
    for (int k = 0; k < NHID + 1; k++) acc[t][k] = 0.f;
    if (t < NHID * NOUT) sW[t] = W2[t];
    if (t < NHID) sb[t] = b1[t];
    __syncthreads();
    int s0 = boff[b], c = bcnt[b];
    for (int j = t; j < c; j += BW) {
        unsigned int p = bucketed[s0 + j];
        int s = p >> BSHIFT, dl = p & (BW - 1);
        const float4* hp = (const float4*)(hs1 + (size_t)s * NHID);
        float4 v0 = hp[0], v1 = hp[1], v2 = hp[2], v3 = hp[3];
        float* a = acc[dl];
        atomicAdd(a + 0, v0.x);  atomicAdd(a + 1, v0.y);
        atomicAdd(a + 2, v0.z);  atomicAdd(a + 3, v0.w);
        atomicAdd(a + 4, v1.x);  atomicAdd(a + 5, v1.y);
        atomicAdd(a + 6, v1.z);  atomicAdd(a + 7, v1.w);
        atomicAdd(a + 8, v2.x);  atomicAdd(a + 9, v2.y);
        atomicAdd(a + 10, v2.z); atomicAdd(a + 11, v2.w);
        atomicAdd(a + 12, v3.x); atomicAdd(a + 13, v3.y);
        atomicAdd(a + 14, v3.z); atomicAdd(a + 15, v3.w);
    }
    __syncthreads();
    int node = (b << BSHIFT) + t;
    if (node >= n) return;
    float di = dinv[node];
    float sv[NHID];
    {
        const float4* sp = (const float4*)(hs1 + (size_t)node * NHID);
        float4 a0 = sp[0], a1 = sp[1], a2 = sp[2], a3 = sp[3];
        sv[0] = a0.x;  sv[1] = a0.y;  sv[2] = a0.z;  sv[3] = a0.w;
        sv[4] = a1.x;  sv[5] = a1.y;  sv[6] = a1.z;  sv[7] = a1.w;
        sv[8] = a2.x;  sv[9] = a2.y;  sv[10] = a2.z; sv[11] = a2.w;
        sv[12] = a3.x; sv[13] = a3.y; sv[14] = a3.z; sv[15] = a3.w;
    }
    float z[NHID];
#pragma unroll
    for (int k = 0; k < NHID; k++)
        z[k] = fmaxf((acc[t][k] + sv[k]) * di + sb[k], 0.0f);
#pragma unroll
    for (int kk = 0; kk < NOUT; kk++) {
        float h = 0.f;
#pragma unroll
        for (int j = 0; j < NHID; j++) h += z[j] * sW[j * NOUT + kk];
        hs2[(size_t)node * 8 + kk] = h * di;
    }
    hs2[(size_t)node * 8 + 6] = 0.f;
    hs2[(size_t)node * 8 + 7] = 0.f;
}

// bucket-centric aggregate layer2 + bias + log_softmax
__global__ void k_agg2(const unsigned int* __restrict__ bucketed, const int* __restrict__ boff,
                       const int* __restrict__ bcnt, const float* __restrict__ hs2,
                       const float* __restrict__ b2, const float* __restrict__ dinv,
                       float* __restrict__ out, int n) {
    __shared__ float acc[BW][NOUT + 1];   // stride 7 -> odd, conflict-free
    __shared__ float sb[NOUT];
    int b = blockIdx.x, t = threadIdx.x;
#pragma unroll
    for (int k = 0; k < NOUT + 1; k++) acc[t][k] = 0.f;
    if (t < NOUT) sb[t] = b2[t];
    __syncthreads();
    int s0 = boff[b], c = bcnt[b];
    for (int j = t; j < c; j += BW) {
        unsigned int p = bucketed[s0 + j];
        int s = p >> BSHIFT, dl = p & (BW - 1);
        const float4* gp = (const float4*)(hs2 + (size_t)s * 8);
        float4 g0 = gp[0], g1 = gp[1];
        float* a = acc[dl];
        atomicAdd(a + 0, g0.x); atomicAdd(a + 1, g0.y);
        atomicAdd(a + 2, g0.z); atomicAdd(a + 3, g0.w);
        atomicAdd(a + 4, g1.x); atomicAdd(a + 5, g1.y);
    }
    __syncthreads();
    int node = (b << BSHIFT) + t;
    if (node >= n) return;
    float di = dinv[node];
    const float4* sp = (const float4*)(hs2 + (size_t)node * 8);
    float4 s0v = sp[0], s1v = sp[1];
    float self[NOUT] = {s0v.x, s0v.y, s0v.z, s0v.w, s1v.x, s1v.y};
    float v[NOUT];
    float m = -1e30f;
#pragma unroll
    for (int k = 0; k < NOUT; k++) {
        v[k] = (acc[t][k] + self[k]) * di + sb[k];
        m = fmaxf(m, v[k]);
    }
    float se = 0.f;
#pragma unroll
    for (int k = 0; k < NOUT; k++) se += expf(v[k] - m);
    float l = logf(se);
#pragma unroll
    for (int k = 0; k < NOUT; k++) out[(size_t)node * NOUT + k] = v[k] - m - l;
}

extern "C" void kernel_launch(void* const* d_in, const int* in_sizes, int n_in,
                              void* d_out, int out_size, void* d_ws, size_t ws_size,
                              hipStream_t stream) {
    const float* x  = (const float*)d_in[0];
    const int*   ei = (const int*)d_in[1];
    const float* W1 = (const float*)d_in[2];
    const float* b1 = (const float*)d_in[3];
    const float* W2 = (const float*)d_in[4];
    const float* b2 = (const float*)d_in[5];
    float* out = (float*)d_out;

    int n  = in_sizes[0] / NFEAT_IN;   // 200000
    int ne = in_sizes[1] / 2;          // 6400000
    const int* src = ei;
    const int* dst = ei + ne;

    char* base = (char*)d_ws;
    size_t off = 0;
    auto alloc = [&](size_t bytes) {
        void* p = base + off;
        off += (bytes + 63) & ~(size_t)63;
        return p;
    };
    int*   bcnt     = (int*)alloc(NBMAX * 4);
    int*   boff     = (int*)alloc(NBMAX * 4);
    int*   bcur     = (int*)alloc(NBMAX * 4);
    unsigned int* bucketed = (unsigned int*)alloc((size_t)ne * 4);
    float* dinv     = (float*)alloc((size_t)n * 4);
    float* hs1      = (float*)alloc((size_t)n * NHID * 4);
    float* hs2      = (float*)alloc((size_t)n * 8 * 4);

    int nb = (n + BW - 1) >> BSHIFT;          // 782
    int gp = (ne + CHUNK - 1) / CHUNK;        // 782
    int gn = (n + 255) / 256;

    k_zero<<<(NBMAX + 255) / 256, 256, 0, stream>>>(bcnt, NBMAX);
    k_hist<<<256, 256, 0, stream>>>(dst, bcnt, ne);
    k_scan<<<1, NBMAX, 0, stream>>>(bcnt, boff, bcur);
    k_partition<<<gp, PB, 0, stream>>>(src, dst, bcur, bucketed, ne);
    k_bucket_dinv<<<nb, BW, 0, stream>>>(bucketed, boff, bcnt, dinv, n);
    k_dense1<<<gn, 256, 0, stream>>>(x, W1, dinv, hs1, n);
    k_agg1<<<nb, BW, 0, stream>>>(bucketed, boff, bcnt, hs1, b1, W2, dinv, hs2, n);
    k_agg2<<<nb, BW, 0, stream>>>(bucketed, boff, bcnt, hs2, b2, dinv, out, n);
}

// Round 4
// 1082.661 us; speedup vs baseline: 6.9130x; 1.1051x over previous
//
#include <hip/hip_runtime.h>
#include <hip/hip_fp16.h>

#define NFEAT_IN 21
#define NHID 16
#define NOUT 6
#define BSHIFT 7
#define BW (1 << BSHIFT)     // 128 nodes per bucket
#define NBMAX 2048           // supports n <= 262144
#define EPT 32
#define PB 256
#define CHUNK (PB * EPT)     // 8192 edges per partition block

__global__ void k_zero(int* __restrict__ p, int n) {
    int i = blockIdx.x * blockDim.x + threadIdx.x;
    if (i < n) p[i] = 0;
}

__global__ void k_hist(const int* __restrict__ dst, int* __restrict__ bcnt, int ne) {
    __shared__ int lcnt[NBMAX];
    for (int t = threadIdx.x; t < NBMAX; t += blockDim.x) lcnt[t] = 0;
    __syncthreads();
    int stride = gridDim.x * blockDim.x;
    for (int e = blockIdx.x * blockDim.x + threadIdx.x; e < ne; e += stride)
        atomicAdd(&lcnt[dst[e] >> BSHIFT], 1);
    __syncthreads();
    for (int t = threadIdx.x; t < NBMAX; t += blockDim.x)
        if (lcnt[t]) atomicAdd(&bcnt[t], lcnt[t]);
}

// scan 2048 entries with 1024 threads (2 per thread)
__global__ void k_scan(const int* __restrict__ bcnt, int* __restrict__ boff,
                       int* __restrict__ bcur) {
    __shared__ int s[1024];
    int t = threadIdx.x;
    int v0 = bcnt[2 * t], v1 = bcnt[2 * t + 1];
    int pair = v0 + v1;
    s[t] = pair;
    __syncthreads();
    for (int off = 1; off < 1024; off <<= 1) {
        int tv = (t >= off) ? s[t - off] : 0;
        __syncthreads();
        s[t] += tv;
        __syncthreads();
    }
    int ex = s[t] - pair;
    boff[2 * t] = ex;      bcur[2 * t] = ex;
    boff[2 * t + 1] = ex + v0;  bcur[2 * t + 1] = ex + v0;
}

__global__ void k_partition(const int* __restrict__ src, const int* __restrict__ dst,
                            int* __restrict__ bcur, unsigned int* __restrict__ bucketed,
                            int ne) {
    __shared__ unsigned int ebd[CHUNK];   // (bucket<<16)|dst_local
    __shared__ int lcnt[NBMAX];
    __shared__ int lbase[NBMAX];
    __shared__ int lcur[NBMAX];
    int t = threadIdx.x;
    long base = (long)blockIdx.x * CHUNK;
    for (int b = t; b < NBMAX; b += PB) lcnt[b] = 0;
    __syncthreads();
#pragma unroll
    for (int k = 0; k < EPT; k++) {
        int idx = t + k * PB;
        long e = base + idx;
        unsigned int v = 0xFFFF0000u;
        if (e < ne) {
            int d = dst[e];
            int b = d >> BSHIFT;
            v = ((unsigned int)b << 16) | (unsigned int)(d & (BW - 1));
            atomicAdd(&lcnt[b], 1);
        }
        ebd[idx] = v;
    }
    __syncthreads();
    for (int b = t; b < NBMAX; b += PB) {
        int c = lcnt[b];
        if (c > 0) lbase[b] = atomicAdd(&bcur[b], c);
        lcur[b] = 0;
    }
    __syncthreads();
#pragma unroll
    for (int k = 0; k < EPT; k++) {
        int idx = t + k * PB;
        unsigned int v = ebd[idx];
        unsigned int b = v >> 16;
        if (b == 0xFFFFu) continue;
        int r = atomicAdd(&lcur[b], 1);
        int s = src[base + idx];
        bucketed[lbase[b] + r] = ((unsigned int)s << BSHIFT) | (v & (BW - 1));
    }
}

__global__ void k_bucket_dinv(const unsigned int* __restrict__ bucketed,
                              const int* __restrict__ boff, const int* __restrict__ bcnt,
                              float* __restrict__ dinv, int n) {
    __shared__ int deg[BW];
    int b = blockIdx.x, t = threadIdx.x;
    if (t < BW) deg[t] = 0;
    __syncthreads();
    int s0 = boff[b], c = bcnt[b];
    for (int j = t; j < c; j += blockDim.x) atomicAdd(&deg[bucketed[s0 + j] & (BW - 1)], 1);
    __syncthreads();
    if (t < BW) {
        int node = (b << BSHIFT) + t;
        if (node < n) dinv[node] = rsqrtf((float)deg[t] + 1.0f);
    }
}

// hs1h = fp16((x @ W1) * dinv[i]) — 16 halves (32B) per node
__global__ void k_dense1(const float* __restrict__ x, const float* __restrict__ W1,
                         const float* __restrict__ dinv, __half2* __restrict__ hs1h, int n) {
    __shared__ float sW[NFEAT_IN * NHID];
    for (int t = threadIdx.x; t < NFEAT_IN * NHID; t += blockDim.x) sW[t] = W1[t];
    __syncthreads();
    int i = blockIdx.x * blockDim.x + threadIdx.x;
    if (i >= n) return;
    float xi[NFEAT_IN];
#pragma unroll
    for (int k = 0; k < NFEAT_IN; k++) xi[k] = x[(size_t)i * NFEAT_IN + k];
    float di = dinv[i];
    float r[NHID];
#pragma unroll
    for (int j = 0; j < NHID; j++) {
        float acc = 0.f;
#pragma unroll
        for (int k = 0; k < NFEAT_IN; k++) acc += xi[k] * sW[k * NHID + j];
        r[j] = acc * di;
    }
    __half2* hp = hs1h + (size_t)i * 8;
#pragma unroll
    for (int q = 0; q < 8; q++) hp[q] = __floats2half2_rn(r[2 * q], r[2 * q + 1]);
}

__device__ __forceinline__ void acc16(float* a, uint4 u0, uint4 u1) {
    unsigned int us[8] = {u0.x, u0.y, u0.z, u0.w, u1.x, u1.y, u1.z, u1.w};
#pragma unroll
    for (int q = 0; q < 8; q++) {
        float2 f = __half22float2(*(const __half2*)&us[q]);
        atomicAdd(a + 2 * q, f.x);
        atomicAdd(a + 2 * q + 1, f.y);
    }
}

// bucket-centric aggregate layer1 + relu + dense2; out hs2h = 8 halves (16B) per node
__global__ __launch_bounds__(256) void
k_agg1(const unsigned int* __restrict__ bucketed, const int* __restrict__ boff,
       const int* __restrict__ bcnt, const __half2* __restrict__ hs1h,
       const float* __restrict__ b1, const float* __restrict__ W2,
       const float* __restrict__ dinv, __half2* __restrict__ hs2h, int n) {
    __shared__ float acc[BW * 17];
    __shared__ float sW[NHID * NOUT];
    __shared__ float sb[NHID];
    int b = blockIdx.x, t = threadIdx.x;
    for (int k = t; k < BW * 17; k += 256) acc[k] = 0.f;
    if (t < NHID * NOUT) sW[t] = W2[t];
    if (t < NHID) sb[t] = b1[t];
    __syncthreads();
    int s0 = boff[b], c = bcnt[b];
    const char* hbase = (const char*)hs1h;
    int j = t;
    for (; j + 256 < c; j += 512) {
        unsigned int p0 = bucketed[s0 + j];
        unsigned int p1 = bucketed[s0 + j + 256];
        const uint4* a0 = (const uint4*)(hbase + (size_t)(p0 >> BSHIFT) * 32);
        const uint4* a1 = (const uint4*)(hbase + (size_t)(p1 >> BSHIFT) * 32);
        uint4 u00 = a0[0], u01 = a0[1];
        uint4 u10 = a1[0], u11 = a1[1];
        acc16(acc + (p0 & (BW - 1)) * 17, u00, u01);
        acc16(acc + (p1 & (BW - 1)) * 17, u10, u11);
    }
    for (; j < c; j += 256) {
        unsigned int p0 = bucketed[s0 + j];
        const uint4* a0 = (const uint4*)(hbase + (size_t)(p0 >> BSHIFT) * 32);
        uint4 u00 = a0[0], u01 = a0[1];
        acc16(acc + (p0 & (BW - 1)) * 17, u00, u01);
    }
    __syncthreads();
    if (t >= BW) return;
    int node = (b << BSHIFT) + t;
    if (node >= n) return;
    float di = dinv[node];
    float z[NHID];
    {
        const uint4* sp = (const uint4*)(hbase + (size_t)node * 32);
        uint4 s0v = sp[0], s1v = sp[1];
        unsigned int us[8] = {s0v.x, s0v.y, s0v.z, s0v.w, s1v.x, s1v.y, s1v.z, s1v.w};
        float* a = acc + t * 17;
#pragma unroll
        for (int q = 0; q < 8; q++) {
            float2 f = __half22float2(*(const __half2*)&us[q]);
            z[2 * q]     = fmaxf((a[2 * q] + f.x) * di + sb[2 * q], 0.0f);
            z[2 * q + 1] = fmaxf((a[2 * q + 1] + f.y) * di + sb[2 * q + 1], 0.0f);
        }
    }
    float h[8];
#pragma unroll
    for (int kk = 0; kk < NOUT; kk++) {
        float s = 0.f;
#pragma unroll
        for (int jj = 0; jj < NHID; jj++) s += z[jj] * sW[jj * NOUT + kk];
        h[kk] = s * di;
    }
    h[6] = 0.f; h[7] = 0.f;
    __half2* op = hs2h + (size_t)node * 4;
#pragma unroll
    for (int q = 0; q < 4; q++) op[q] = __floats2half2_rn(h[2 * q], h[2 * q + 1]);
}

// bucket-centric aggregate layer2 + bias + log_softmax
__global__ __launch_bounds__(256) void
k_agg2(const unsigned int* __restrict__ bucketed, const int* __restrict__ boff,
       const int* __restrict__ bcnt, const __half2* __restrict__ hs2h,
       const float* __restrict__ b2, const float* __restrict__ dinv,
       float* __restrict__ out, int n) {
    __shared__ float acc[BW * 7];
    __shared__ float sb[NOUT];
    int b = blockIdx.x, t = threadIdx.x;
    for (int k = t; k < BW * 7; k += 256) acc[k] = 0.f;
    if (t < NOUT) sb[t] = b2[t];
    __syncthreads();
    int s0 = boff[b], c = bcnt[b];
    const char* hbase = (const char*)hs2h;
    int j = t;
    for (; j + 256 < c; j += 512) {
        unsigned int p0 = bucketed[s0 + j];
        unsigned int p1 = bucketed[s0 + j + 256];
        uint4 u0 = *(const uint4*)(hbase + (size_t)(p0 >> BSHIFT) * 16);
        uint4 u1 = *(const uint4*)(hbase + (size_t)(p1 >> BSHIFT) * 16);
        {
            float* a = acc + (p0 & (BW - 1)) * 7;
            unsigned int us[3] = {u0.x, u0.y, u0.z};
#pragma unroll
            for (int q = 0; q < 3; q++) {
                float2 f = __half22float2(*(const __half2*)&us[q]);
                atomicAdd(a + 2 * q, f.x);
                atomicAdd(a + 2 * q + 1, f.y);
            }
        }
        {
            float* a = acc + (p1 & (BW - 1)) * 7;
            unsigned int us[3] = {u1.x, u1.y, u1.z};
#pragma unroll
            for (int q = 0; q < 3; q++) {
                float2 f = __half22float2(*(const __half2*)&us[q]);
                atomicAdd(a + 2 * q, f.x);
                atomicAdd(a + 2 * q + 1, f.y);
            }
        }
    }
    for (; j < c; j += 256) {
        unsigned int p0 = bucketed[s0 + j];
        uint4 u0 = *(const uint4*)(hbase + (size_t)(p0 >> BSHIFT) * 16);
        float* a = acc + (p0 & (BW - 1)) * 7;
        unsigned int us[3] = {u0.x, u0.y, u0.z};
#pragma unroll
        for (int q = 0; q < 3; q++) {
            float2 f = __half22float2(*(const __half2*)&us[q]);
            atomicAdd(a + 2 * q, f.x);
            atomicAdd(a + 2 * q + 1, f.y);
        }
    }
    __syncthreads();
    if (t >= BW) return;
    int node = (b << BSHIFT) + t;
    if (node >= n) return;
    float di = dinv[node];
    uint4 sv = *(const uint4*)(hbase + (size_t)node * 16);
    unsigned int us[3] = {sv.x, sv.y, sv.z};
    float v[NOUT];
    float* a = acc + t * 7;
#pragma unroll
    for (int q = 0; q < 3; q++) {
        float2 f = __half22float2(*(const __half2*)&us[q]);
        v[2 * q]     = (a[2 * q] + f.x) * di + sb[2 * q];
        v[2 * q + 1] = (a[2 * q + 1] + f.y) * di + sb[2 * q + 1];
    }
    float m = -1e30f;
#pragma unroll
    for (int k = 0; k < NOUT; k++) m = fmaxf(m, v[k]);
    float se = 0.f;
#pragma unroll
    for (int k = 0; k < NOUT; k++) se += expf(v[k] - m);
    float l = logf(se);
#pragma unroll
    for (int k = 0; k < NOUT; k++) out[(size_t)node * NOUT + k] = v[k] - m - l;
}

extern "C" void kernel_launch(void* const* d_in, const int* in_sizes, int n_in,
                              void* d_out, int out_size, void* d_ws, size_t ws_size,
                              hipStream_t stream) {
    const float* x  = (const float*)d_in[0];
    const int*   ei = (const int*)d_in[1];
    const float* W1 = (const float*)d_in[2];
    const float* b1 = (const float*)d_in[3];
    const float* W2 = (const float*)d_in[4];
    const float* b2 = (const float*)d_in[5];
    float* out = (float*)d_out;

    int n  = in_sizes[0] / NFEAT_IN;   // 200000
    int ne = in_sizes[1] / 2;          // 6400000
    const int* src = ei;
    const int* dst = ei + ne;

    char* base = (char*)d_ws;
    size_t off = 0;
    auto alloc = [&](size_t bytes) {
        void* p = base + off;
        off += (bytes + 63) & ~(size_t)63;
        return p;
    };
    int* bcnt = (int*)alloc(NBMAX * 4);
    int* boff = (int*)alloc(NBMAX * 4);
    int* bcur = (int*)alloc(NBMAX * 4);
    unsigned int* bucketed = (unsigned int*)alloc((size_t)ne * 4);
    float*   dinv = (float*)alloc((size_t)n * 4);
    __half2* hs1h = (__half2*)alloc((size_t)n * 32);
    __half2* hs2h = (__half2*)alloc((size_t)n * 16);

    int nb = (n + BW - 1) >> BSHIFT;          // 1563
    int gp = (ne + CHUNK - 1) / CHUNK;        // 782
    int gn = (n + 255) / 256;

    k_zero<<<(NBMAX + 255) / 256, 256, 0, stream>>>(bcnt, NBMAX);
    k_hist<<<256, 256, 0, stream>>>(dst, bcnt, ne);
    k_scan<<<1, 1024, 0, stream>>>(bcnt, boff, bcur);
    k_partition<<<gp, PB, 0, stream>>>(src, dst, bcur, bucketed, ne);
    k_bucket_dinv<<<nb, 256, 0, stream>>>(bucketed, boff, bcnt, dinv, n);
    k_dense1<<<gn, 256, 0, stream>>>(x, W1, dinv, hs1h, n);
    k_agg1<<<nb, 256, 0, stream>>>(bucketed, boff, bcnt, hs1h, b1, W2, dinv, hs2h, n);
    k_agg2<<<nb, 256, 0, stream>>>(bucketed, boff, bcnt, hs2h, b2, dinv, out, n);
}

// Round 5
// 1075.068 us; speedup vs baseline: 6.9619x; 1.0071x over previous
//
#include <hip/hip_runtime.h>
#include <hip/hip_fp16.h>

#define NFEAT_IN 21
#define NHID 16
#define NOUT 6
#define BSHIFT 7
#define BW (1 << BSHIFT)     // 128 nodes per bucket
#define NBMAX 2048           // supports n <= 262144
#define EPT 32
#define PB 256
#define CHUNK (PB * EPT)     // 8192 edges per partition block
#define DEPTH 8

__global__ void k_zero(int* __restrict__ p, int n) {
    int i = blockIdx.x * blockDim.x + threadIdx.x;
    if (i < n) p[i] = 0;
}

__global__ void k_hist(const int* __restrict__ dst, int* __restrict__ bcnt, int ne) {
    __shared__ int lcnt[NBMAX];
    for (int t = threadIdx.x; t < NBMAX; t += blockDim.x) lcnt[t] = 0;
    __syncthreads();
    int stride = gridDim.x * blockDim.x;
    for (int e = blockIdx.x * blockDim.x + threadIdx.x; e < ne; e += stride)
        atomicAdd(&lcnt[dst[e] >> BSHIFT], 1);
    __syncthreads();
    for (int t = threadIdx.x; t < NBMAX; t += blockDim.x)
        if (lcnt[t]) atomicAdd(&bcnt[t], lcnt[t]);
}

// scan 2048 entries with 1024 threads (2 per thread)
__global__ void k_scan(const int* __restrict__ bcnt, int* __restrict__ boff,
                       int* __restrict__ bcur) {
    __shared__ int s[1024];
    int t = threadIdx.x;
    int v0 = bcnt[2 * t], v1 = bcnt[2 * t + 1];
    int pair = v0 + v1;
    s[t] = pair;
    __syncthreads();
    for (int off = 1; off < 1024; off <<= 1) {
        int tv = (t >= off) ? s[t - off] : 0;
        __syncthreads();
        s[t] += tv;
        __syncthreads();
    }
    int ex = s[t] - pair;
    boff[2 * t] = ex;      bcur[2 * t] = ex;
    boff[2 * t + 1] = ex + v0;  bcur[2 * t + 1] = ex + v0;
}

__global__ void k_partition(const int* __restrict__ src, const int* __restrict__ dst,
                            int* __restrict__ bcur, unsigned int* __restrict__ bucketed,
                            int ne) {
    __shared__ unsigned int ebd[CHUNK];   // (bucket<<16)|dst_local
    __shared__ int lcnt[NBMAX];
    __shared__ int lbase[NBMAX];
    __shared__ int lcur[NBMAX];
    int t = threadIdx.x;
    long base = (long)blockIdx.x * CHUNK;
    for (int b = t; b < NBMAX; b += PB) lcnt[b] = 0;
    __syncthreads();
#pragma unroll
    for (int k = 0; k < EPT; k++) {
        int idx = t + k * PB;
        long e = base + idx;
        unsigned int v = 0xFFFF0000u;
        if (e < ne) {
            int d = dst[e];
            int b = d >> BSHIFT;
            v = ((unsigned int)b << 16) | (unsigned int)(d & (BW - 1));
            atomicAdd(&lcnt[b], 1);
        }
        ebd[idx] = v;
    }
    __syncthreads();
    for (int b = t; b < NBMAX; b += PB) {
        int c = lcnt[b];
        if (c > 0) lbase[b] = atomicAdd(&bcur[b], c);
        lcur[b] = 0;
    }
    __syncthreads();
#pragma unroll
    for (int k = 0; k < EPT; k++) {
        int idx = t + k * PB;
        unsigned int v = ebd[idx];
        unsigned int b = v >> 16;
        if (b == 0xFFFFu) continue;
        int r = atomicAdd(&lcur[b], 1);
        int s = src[base + idx];
        bucketed[lbase[b] + r] = ((unsigned int)s << BSHIFT) | (v & (BW - 1));
    }
}

__global__ void k_bucket_dinv(const unsigned int* __restrict__ bucketed,
                              const int* __restrict__ boff, const int* __restrict__ bcnt,
                              float* __restrict__ dinv, int n) {
    __shared__ int deg[BW];
    int b = blockIdx.x, t = threadIdx.x;
    if (t < BW) deg[t] = 0;
    __syncthreads();
    int s0 = boff[b], c = bcnt[b];
    for (int j = t; j < c; j += blockDim.x) atomicAdd(&deg[bucketed[s0 + j] & (BW - 1)], 1);
    __syncthreads();
    if (t < BW) {
        int node = (b << BSHIFT) + t;
        if (node < n) dinv[node] = rsqrtf((float)deg[t] + 1.0f);
    }
}

// hs1h = fp16((x @ W1) * dinv[i]) — 16 halves (32B) per node
__global__ void k_dense1(const float* __restrict__ x, const float* __restrict__ W1,
                         const float* __restrict__ dinv, __half2* __restrict__ hs1h, int n) {
    __shared__ float sW[NFEAT_IN * NHID];
    for (int t = threadIdx.x; t < NFEAT_IN * NHID; t += blockDim.x) sW[t] = W1[t];
    __syncthreads();
    int i = blockIdx.x * blockDim.x + threadIdx.x;
    if (i >= n) return;
    float xi[NFEAT_IN];
#pragma unroll
    for (int k = 0; k < NFEAT_IN; k++) xi[k] = x[(size_t)i * NFEAT_IN + k];
    float di = dinv[i];
    float r[NHID];
#pragma unroll
    for (int j = 0; j < NHID; j++) {
        float acc = 0.f;
#pragma unroll
        for (int k = 0; k < NFEAT_IN; k++) acc += xi[k] * sW[k * NHID + j];
        r[j] = acc * di;
    }
    __half2* hp = hs1h + (size_t)i * 8;
#pragma unroll
    for (int q = 0; q < 8; q++) hp[q] = __floats2half2_rn(r[2 * q], r[2 * q + 1]);
}

__device__ __forceinline__ void acc16(float* a, uint4 u0, uint4 u1) {
    unsigned int us[8] = {u0.x, u0.y, u0.z, u0.w, u1.x, u1.y, u1.z, u1.w};
#pragma unroll
    for (int q = 0; q < 8; q++) {
        float2 f = __half22float2(*(const __half2*)&us[q]);
        atomicAdd(a + 2 * q, f.x);
        atomicAdd(a + 2 * q + 1, f.y);
    }
}

// bucket-centric aggregate layer1 + relu + dense2; depth-8 pipelined gathers
__global__ __launch_bounds__(256, 4) void
k_agg1(const unsigned int* __restrict__ bucketed, const int* __restrict__ boff,
       const int* __restrict__ bcnt, const __half2* __restrict__ hs1h,
       const float* __restrict__ b1, const float* __restrict__ W2,
       const float* __restrict__ dinv, __half2* __restrict__ hs2h, int n) {
    __shared__ float acc[BW * 17];
    __shared__ float sW[NHID * NOUT];
    __shared__ float sb[NHID];
    int b = blockIdx.x, t = threadIdx.x;
    for (int k = t; k < BW * 17; k += 256) acc[k] = 0.f;
    if (t < NHID * NOUT) sW[t] = W2[t];
    if (t < NHID) sb[t] = b1[t];
    __syncthreads();
    int s0 = boff[b], c = bcnt[b];
    const char* hbase = (const char*)hs1h;
    int nIter = (c - t + 255) >> 8;    // edges this thread handles (j = t + k*256 < c)
    for (int k0 = 0; k0 < nIter; k0 += DEPTH) {
        unsigned int pk[DEPTH];
        uint4 f0[DEPTH], f1[DEPTH];
#pragma unroll
        for (int q = 0; q < DEPTH; q++) {
            int j = t + (k0 + q) * 256;
            int jj = (k0 + q < nIter) ? (s0 + j) : s0;   // clamp to safe addr
            pk[q] = __builtin_nontemporal_load(bucketed + jj);
        }
#pragma unroll
        for (int q = 0; q < DEPTH; q++) {
            const uint4* a = (const uint4*)(hbase + (size_t)(pk[q] >> BSHIFT) * 32);
            f0[q] = a[0];
            f1[q] = a[1];
        }
#pragma unroll
        for (int q = 0; q < DEPTH; q++) {
            if (k0 + q < nIter)
                acc16(acc + (pk[q] & (BW - 1)) * 17, f0[q], f1[q]);
        }
    }
    __syncthreads();
    if (t >= BW) return;
    int node = (b << BSHIFT) + t;
    if (node >= n) return;
    float di = dinv[node];
    float z[NHID];
    {
        const uint4* sp = (const uint4*)(hbase + (size_t)node * 32);
        uint4 s0v = sp[0], s1v = sp[1];
        unsigned int us[8] = {s0v.x, s0v.y, s0v.z, s0v.w, s1v.x, s1v.y, s1v.z, s1v.w};
        float* a = acc + t * 17;
#pragma unroll
        for (int q = 0; q < 8; q++) {
            float2 f = __half22float2(*(const __half2*)&us[q]);
            z[2 * q]     = fmaxf((a[2 * q] + f.x) * di + sb[2 * q], 0.0f);
            z[2 * q + 1] = fmaxf((a[2 * q + 1] + f.y) * di + sb[2 * q + 1], 0.0f);
        }
    }
    float h[8];
#pragma unroll
    for (int kk = 0; kk < NOUT; kk++) {
        float s = 0.f;
#pragma unroll
        for (int jj = 0; jj < NHID; jj++) s += z[jj] * sW[jj * NOUT + kk];
        h[kk] = s * di;
    }
    h[6] = 0.f; h[7] = 0.f;
    __half2* op = hs2h + (size_t)node * 4;
#pragma unroll
    for (int q = 0; q < 4; q++) op[q] = __floats2half2_rn(h[2 * q], h[2 * q + 1]);
}

// bucket-centric aggregate layer2 + bias + log_softmax; depth-8 pipelined gathers
__global__ __launch_bounds__(256, 4) void
k_agg2(const unsigned int* __restrict__ bucketed, const int* __restrict__ boff,
       const int* __restrict__ bcnt, const __half2* __restrict__ hs2h,
       const float* __restrict__ b2, const float* __restrict__ dinv,
       float* __restrict__ out, int n) {
    __shared__ float acc[BW * 7];
    __shared__ float sb[NOUT];
    int b = blockIdx.x, t = threadIdx.x;
    for (int k = t; k < BW * 7; k += 256) acc[k] = 0.f;
    if (t < NOUT) sb[t] = b2[t];
    __syncthreads();
    int s0 = boff[b], c = bcnt[b];
    const char* hbase = (const char*)hs2h;
    int nIter = (c - t + 255) >> 8;
    for (int k0 = 0; k0 < nIter; k0 += DEPTH) {
        unsigned int pk[DEPTH];
        uint4 f[DEPTH];
#pragma unroll
        for (int q = 0; q < DEPTH; q++) {
            int j = t + (k0 + q) * 256;
            int jj = (k0 + q < nIter) ? (s0 + j) : s0;
            pk[q] = __builtin_nontemporal_load(bucketed + jj);
        }
#pragma unroll
        for (int q = 0; q < DEPTH; q++)
            f[q] = *(const uint4*)(hbase + (size_t)(pk[q] >> BSHIFT) * 16);
#pragma unroll
        for (int q = 0; q < DEPTH; q++) {
            if (k0 + q < nIter) {
                float* a = acc + (pk[q] & (BW - 1)) * 7;
                unsigned int us[3] = {f[q].x, f[q].y, f[q].z};
#pragma unroll
                for (int w = 0; w < 3; w++) {
                    float2 fv = __half22float2(*(const __half2*)&us[w]);
                    atomicAdd(a + 2 * w, fv.x);
                    atomicAdd(a + 2 * w + 1, fv.y);
                }
            }
        }
    }
    __syncthreads();
    if (t >= BW) return;
    int node = (b << BSHIFT) + t;
    if (node >= n) return;
    float di = dinv[node];
    uint4 sv = *(const uint4*)(hbase + (size_t)node * 16);
    unsigned int us[3] = {sv.x, sv.y, sv.z};
    float v[NOUT];
    float* a = acc + t * 7;
#pragma unroll
    for (int q = 0; q < 3; q++) {
        float2 f = __half22float2(*(const __half2*)&us[q]);
        v[2 * q]     = (a[2 * q] + f.x) * di + sb[2 * q];
        v[2 * q + 1] = (a[2 * q + 1] + f.y) * di + sb[2 * q + 1];
    }
    float m = -1e30f;
#pragma unroll
    for (int k = 0; k < NOUT; k++) m = fmaxf(m, v[k]);
    float se = 0.f;
#pragma unroll
    for (int k = 0; k < NOUT; k++) se += expf(v[k] - m);
    float l = logf(se);
#pragma unroll
    for (int k = 0; k < NOUT; k++) out[(size_t)node * NOUT + k] = v[k] - m - l;
}

extern "C" void kernel_launch(void* const* d_in, const int* in_sizes, int n_in,
                              void* d_out, int out_size, void* d_ws, size_t ws_size,
                              hipStream_t stream) {
    const float* x  = (const float*)d_in[0];
    const int*   ei = (const int*)d_in[1];
    const float* W1 = (const float*)d_in[2];
    const float* b1 = (const float*)d_in[3];
    const float* W2 = (const float*)d_in[4];
    const float* b2 = (const float*)d_in[5];
    float* out = (float*)d_out;

    int n  = in_sizes[0] / NFEAT_IN;   // 200000
    int ne = in_sizes[1] / 2;          // 6400000
    const int* src = ei;
    const int* dst = ei + ne;

    char* base = (char*)d_ws;
    size_t off = 0;
    auto alloc = [&](size_t bytes) {
        void* p = base + off;
        off += (bytes + 63) & ~(size_t)63;
        return p;
    };
    int* bcnt = (int*)alloc(NBMAX * 4);
    int* boff = (int*)alloc(NBMAX * 4);
    int* bcur = (int*)alloc(NBMAX * 4);
    unsigned int* bucketed = (unsigned int*)alloc((size_t)ne * 4);
    float*   dinv = (float*)alloc((size_t)n * 4);
    __half2* hs1h = (__half2*)alloc((size_t)n * 32);
    __half2* hs2h = (__half2*)alloc((size_t)n * 16);

    int nb = (n + BW - 1) >> BSHIFT;          // 1563
    int gp = (ne + CHUNK - 1) / CHUNK;        // 782
    int gn = (n + 255) / 256;

    k_zero<<<(NBMAX + 255) / 256, 256, 0, stream>>>(bcnt, NBMAX);
    k_hist<<<256, 256, 0, stream>>>(dst, bcnt, ne);
    k_scan<<<1, 1024, 0, stream>>>(bcnt, boff, bcur);
    k_partition<<<gp, PB, 0, stream>>>(src, dst, bcur, bucketed, ne);
    k_bucket_dinv<<<nb, 256, 0, stream>>>(bucketed, boff, bcnt, dinv, n);
    k_dense1<<<gn, 256, 0, stream>>>(x, W1, dinv, hs1h, n);
    k_agg1<<<nb, 256, 0, stream>>>(bucketed, boff, bcnt, hs1h, b1, W2, dinv, hs2h, n);
    k_agg2<<<nb, 256, 0, stream>>>(bucketed, boff, bcnt, hs2h, b2, dinv, out, n);
}

// Round 6
// 1067.233 us; speedup vs baseline: 7.0130x; 1.0073x over previous
//
#include <hip/hip_runtime.h>
#include <hip/hip_fp16.h>

#define NFEAT_IN 21
#define NHID 16
#define NOUT 6
#define BSHIFT 7
#define BW (1 << BSHIFT)     // 128 nodes per bucket
#define NBMAX 2048           // supports n <= 262144
#define EPT 32
#define PB 256
#define CHUNK (PB * EPT)     // 8192 edges per partition block
#define DEPTH 8

__global__ void k_zero(int* __restrict__ p, int n) {
    int i = blockIdx.x * blockDim.x + threadIdx.x;
    if (i < n) p[i] = 0;
}

__global__ void k_hist(const int* __restrict__ dst, int* __restrict__ bcnt, int ne) {
    __shared__ int lcnt[NBMAX];
    for (int t = threadIdx.x; t < NBMAX; t += blockDim.x) lcnt[t] = 0;
    __syncthreads();
    int stride = gridDim.x * blockDim.x;
    for (int e = blockIdx.x * blockDim.x + threadIdx.x; e < ne; e += stride)
        atomicAdd(&lcnt[dst[e] >> BSHIFT], 1);
    __syncthreads();
    for (int t = threadIdx.x; t < NBMAX; t += blockDim.x)
        if (lcnt[t]) atomicAdd(&bcnt[t], lcnt[t]);
}

// scan 2048 entries with 1024 threads (2 per thread)
__global__ void k_scan(const int* __restrict__ bcnt, int* __restrict__ boff,
                       int* __restrict__ bcur) {
    __shared__ int s[1024];
    int t = threadIdx.x;
    int v0 = bcnt[2 * t], v1 = bcnt[2 * t + 1];
    int pair = v0 + v1;
    s[t] = pair;
    __syncthreads();
    for (int off = 1; off < 1024; off <<= 1) {
        int tv = (t >= off) ? s[t - off] : 0;
        __syncthreads();
        s[t] += tv;
        __syncthreads();
    }
    int ex = s[t] - pair;
    boff[2 * t] = ex;      bcur[2 * t] = ex;
    boff[2 * t + 1] = ex + v0;  bcur[2 * t + 1] = ex + v0;
}

__global__ void k_partition(const int* __restrict__ src, const int* __restrict__ dst,
                            int* __restrict__ bcur, unsigned int* __restrict__ bucketed,
                            int ne) {
    __shared__ unsigned int ebd[CHUNK];   // (bucket<<16)|dst_local
    __shared__ int lcnt[NBMAX];
    __shared__ int lbase[NBMAX];
    __shared__ int lcur[NBMAX];
    int t = threadIdx.x;
    long base = (long)blockIdx.x * CHUNK;
    for (int b = t; b < NBMAX; b += PB) lcnt[b] = 0;
    __syncthreads();
#pragma unroll
    for (int k = 0; k < EPT; k++) {
        int idx = t + k * PB;
        long e = base + idx;
        unsigned int v = 0xFFFF0000u;
        if (e < ne) {
            int d = dst[e];
            int b = d >> BSHIFT;
            v = ((unsigned int)b << 16) | (unsigned int)(d & (BW - 1));
            atomicAdd(&lcnt[b], 1);
        }
        ebd[idx] = v;
    }
    __syncthreads();
    for (int b = t; b < NBMAX; b += PB) {
        int c = lcnt[b];
        if (c > 0) lbase[b] = atomicAdd(&bcur[b], c);
        lcur[b] = 0;
    }
    __syncthreads();
#pragma unroll
    for (int k = 0; k < EPT; k++) {
        int idx = t + k * PB;
        unsigned int v = ebd[idx];
        unsigned int b = v >> 16;
        if (b == 0xFFFFu) continue;
        int r = atomicAdd(&lcur[b], 1);
        int s = src[base + idx];
        bucketed[lbase[b] + r] = ((unsigned int)s << BSHIFT) | (v & (BW - 1));
    }
}

__global__ void k_bucket_dinv(const unsigned int* __restrict__ bucketed,
                              const int* __restrict__ boff, const int* __restrict__ bcnt,
                              float* __restrict__ dinv, int n) {
    __shared__ int deg[BW];
    int b = blockIdx.x, t = threadIdx.x;
    if (t < BW) deg[t] = 0;
    __syncthreads();
    int s0 = boff[b], c = bcnt[b];
    for (int j = t; j < c; j += blockDim.x) atomicAdd(&deg[bucketed[s0 + j] & (BW - 1)], 1);
    __syncthreads();
    if (t < BW) {
        int node = (b << BSHIFT) + t;
        if (node < n) dinv[node] = rsqrtf((float)deg[t] + 1.0f);
    }
}

// hs1h = fp16((x @ W1) * dinv[i]) — 16 halves (32B) per node
__global__ void k_dense1(const float* __restrict__ x, const float* __restrict__ W1,
                         const float* __restrict__ dinv, __half2* __restrict__ hs1h, int n) {
    __shared__ float sW[NFEAT_IN * NHID];
    for (int t = threadIdx.x; t < NFEAT_IN * NHID; t += blockDim.x) sW[t] = W1[t];
    __syncthreads();
    int i = blockIdx.x * blockDim.x + threadIdx.x;
    if (i >= n) return;
    float xi[NFEAT_IN];
#pragma unroll
    for (int k = 0; k < NFEAT_IN; k++) xi[k] = x[(size_t)i * NFEAT_IN + k];
    float di = dinv[i];
    float r[NHID];
#pragma unroll
    for (int j = 0; j < NHID; j++) {
        float acc = 0.f;
#pragma unroll
        for (int k = 0; k < NFEAT_IN; k++) acc += xi[k] * sW[k * NHID + j];
        r[j] = acc * di;
    }
    __half2* hp = hs1h + (size_t)i * 8;
#pragma unroll
    for (int q = 0; q < 8; q++) hp[q] = __floats2half2_rn(r[2 * q], r[2 * q + 1]);
}

__device__ __forceinline__ void acc16(float* a, uint4 u0, uint4 u1) {
    unsigned int us[8] = {u0.x, u0.y, u0.z, u0.w, u1.x, u1.y, u1.z, u1.w};
#pragma unroll
    for (int q = 0; q < 8; q++) {
        float2 f = __half22float2(*(const __half2*)&us[q]);
        atomicAdd(a + 2 * q, f.x);
        atomicAdd(a + 2 * q + 1, f.y);
    }
}

// bucket-centric aggregate layer1 + relu + dense2
// launch_bounds(256,2): VGPR cap 256 so the DEPTH-8 gather pipeline (8 idx +
// 16 uint4 payloads ~ 110 VGPR) actually materializes instead of being
// re-serialized by the register allocator (round-5 failure: VGPR=40).
__global__ __launch_bounds__(256, 2) void
k_agg1(const unsigned int* __restrict__ bucketed, const int* __restrict__ boff,
       const int* __restrict__ bcnt, const __half2* __restrict__ hs1h,
       const float* __restrict__ b1, const float* __restrict__ W2,
       const float* __restrict__ dinv, __half2* __restrict__ hs2h, int n) {
    __shared__ float acc[BW * 17];
    __shared__ float sW[NHID * NOUT];
    __shared__ float sb[NHID];
    int b = blockIdx.x, t = threadIdx.x;
    for (int k = t; k < BW * 17; k += 256) acc[k] = 0.f;
    if (t < NHID * NOUT) sW[t] = W2[t];
    if (t < NHID) sb[t] = b1[t];
    __syncthreads();
    int s0 = boff[b], c = bcnt[b];
    const char* hbase = (const char*)hs1h;
    int nIter = (c - t + 255) >> 8;    // j = t + k*256 < c
    int kFull = (nIter / DEPTH) * DEPTH;
    int k0 = 0;
    for (; k0 < kFull; k0 += DEPTH) {
        unsigned int pk[DEPTH];
        uint4 f0[DEPTH], f1[DEPTH];
#pragma unroll
        for (int q = 0; q < DEPTH; q++)
            pk[q] = __builtin_nontemporal_load(bucketed + s0 + t + (k0 + q) * 256);
#pragma unroll
        for (int q = 0; q < DEPTH; q++) {
            const uint4* a = (const uint4*)(hbase + (size_t)(pk[q] >> BSHIFT) * 32);
            f0[q] = a[0];
            f1[q] = a[1];
        }
#pragma unroll
        for (int q = 0; q < DEPTH; q++)
            acc16(acc + (pk[q] & (BW - 1)) * 17, f0[q], f1[q]);
    }
    for (; k0 < nIter; k0++) {
        unsigned int p = __builtin_nontemporal_load(bucketed + s0 + t + k0 * 256);
        const uint4* a = (const uint4*)(hbase + (size_t)(p >> BSHIFT) * 32);
        uint4 u0 = a[0], u1 = a[1];
        acc16(acc + (p & (BW - 1)) * 17, u0, u1);
    }
    __syncthreads();
    if (t >= BW) return;
    int node = (b << BSHIFT) + t;
    if (node >= n) return;
    float di = dinv[node];
    float z[NHID];
    {
        const uint4* sp = (const uint4*)(hbase + (size_t)node * 32);
        uint4 s0v = sp[0], s1v = sp[1];
        unsigned int us[8] = {s0v.x, s0v.y, s0v.z, s0v.w, s1v.x, s1v.y, s1v.z, s1v.w};
        float* a = acc + t * 17;
#pragma unroll
        for (int q = 0; q < 8; q++) {
            float2 f = __half22float2(*(const __half2*)&us[q]);
            z[2 * q]     = fmaxf((a[2 * q] + f.x) * di + sb[2 * q], 0.0f);
            z[2 * q + 1] = fmaxf((a[2 * q + 1] + f.y) * di + sb[2 * q + 1], 0.0f);
        }
    }
    float h[8];
#pragma unroll
    for (int kk = 0; kk < NOUT; kk++) {
        float s = 0.f;
#pragma unroll
        for (int jj = 0; jj < NHID; jj++) s += z[jj] * sW[jj * NOUT + kk];
        h[kk] = s * di;
    }
    h[6] = 0.f; h[7] = 0.f;
    __half2* op = hs2h + (size_t)node * 4;
#pragma unroll
    for (int q = 0; q < 4; q++) op[q] = __floats2half2_rn(h[2 * q], h[2 * q + 1]);
}

// bucket-centric aggregate layer2 + bias + log_softmax; DEPTH-8 pipeline
__global__ __launch_bounds__(256, 4) void
k_agg2(const unsigned int* __restrict__ bucketed, const int* __restrict__ boff,
       const int* __restrict__ bcnt, const __half2* __restrict__ hs2h,
       const float* __restrict__ b2, const float* __restrict__ dinv,
       float* __restrict__ out, int n) {
    __shared__ float acc[BW * 7];
    __shared__ float sb[NOUT];
    int b = blockIdx.x, t = threadIdx.x;
    for (int k = t; k < BW * 7; k += 256) acc[k] = 0.f;
    if (t < NOUT) sb[t] = b2[t];
    __syncthreads();
    int s0 = boff[b], c = bcnt[b];
    const char* hbase = (const char*)hs2h;
    int nIter = (c - t + 255) >> 8;
    int kFull = (nIter / DEPTH) * DEPTH;
    int k0 = 0;
    for (; k0 < kFull; k0 += DEPTH) {
        unsigned int pk[DEPTH];
        uint4 f[DEPTH];
#pragma unroll
        for (int q = 0; q < DEPTH; q++)
            pk[q] = __builtin_nontemporal_load(bucketed + s0 + t + (k0 + q) * 256);
#pragma unroll
        for (int q = 0; q < DEPTH; q++)
            f[q] = *(const uint4*)(hbase + (size_t)(pk[q] >> BSHIFT) * 16);
#pragma unroll
        for (int q = 0; q < DEPTH; q++) {
            float* a = acc + (pk[q] & (BW - 1)) * 7;
            unsigned int us[3] = {f[q].x, f[q].y, f[q].z};
#pragma unroll
            for (int w = 0; w < 3; w++) {
                float2 fv = __half22float2(*(const __half2*)&us[w]);
                atomicAdd(a + 2 * w, fv.x);
                atomicAdd(a + 2 * w + 1, fv.y);
            }
        }
    }
    for (; k0 < nIter; k0++) {
        unsigned int p = __builtin_nontemporal_load(bucketed + s0 + t + k0 * 256);
        uint4 u = *(const uint4*)(hbase + (size_t)(p >> BSHIFT) * 16);
        float* a = acc + (p & (BW - 1)) * 7;
        unsigned int us[3] = {u.x, u.y, u.z};
#pragma unroll
        for (int w = 0; w < 3; w++) {
            float2 fv = __half22float2(*(const __half2*)&us[w]);
            atomicAdd(a + 2 * w, fv.x);
            atomicAdd(a + 2 * w + 1, fv.y);
        }
    }
    __syncthreads();
    if (t >= BW) return;
    int node = (b << BSHIFT) + t;
    if (node >= n) return;
    float di = dinv[node];
    uint4 sv = *(const uint4*)(hbase + (size_t)node * 16);
    unsigned int us[3] = {sv.x, sv.y, sv.z};
    float v[NOUT];
    float* a = acc + t * 7;
#pragma unroll
    for (int q = 0; q < 3; q++) {
        float2 f = __half22float2(*(const __half2*)&us[q]);
        v[2 * q]     = (a[2 * q] + f.x) * di + sb[2 * q];
        v[2 * q + 1] = (a[2 * q + 1] + f.y) * di + sb[2 * q + 1];
    }
    float m = -1e30f;
#pragma unroll
    for (int k = 0; k < NOUT; k++) m = fmaxf(m, v[k]);
    float se = 0.f;
#pragma unroll
    for (int k = 0; k < NOUT; k++) se += expf(v[k] - m);
    float l = logf(se);
#pragma unroll
    for (int k = 0; k < NOUT; k++) out[(size_t)node * NOUT + k] = v[k] - m - l;
}

extern "C" void kernel_launch(void* const* d_in, const int* in_sizes, int n_in,
                              void* d_out, int out_size, void* d_ws, size_t ws_size,
                              hipStream_t stream) {
    const float* x  = (const float*)d_in[0];
    const int*   ei = (const int*)d_in[1];
    const float* W1 = (const float*)d_in[2];
    const float* b1 = (const float*)d_in[3];
    const float* W2 = (const float*)d_in[4];
    const float* b2 = (const float*)d_in[5];
    float* out = (float*)d_out;

    int n  = in_sizes[0] / NFEAT_IN;   // 200000
    int ne = in_sizes[1] / 2;          // 6400000
    const int* src = ei;
    const int* dst = ei + ne;

    char* base = (char*)d_ws;
    size_t off = 0;
    auto alloc = [&](size_t bytes) {
        void* p = base + off;
        off += (bytes + 63) & ~(size_t)63;
        return p;
    };
    int* bcnt = (int*)alloc(NBMAX * 4);
    int* boff = (int*)alloc(NBMAX * 4);
    int* bcur = (int*)alloc(NBMAX * 4);
    unsigned int* bucketed = (unsigned int*)alloc((size_t)ne * 4);
    float*   dinv = (float*)alloc((size_t)n * 4);
    __half2* hs1h = (__half2*)alloc((size_t)n * 32);
    __half2* hs2h = (__half2*)alloc((size_t)n * 16);

    int nb = (n + BW - 1) >> BSHIFT;          // 1563
    int gp = (ne + CHUNK - 1) / CHUNK;        // 782
    int gn = (n + 255) / 256;

    k_zero<<<(NBMAX + 255) / 256, 256, 0, stream>>>(bcnt, NBMAX);
    k_hist<<<256, 256, 0, stream>>>(dst, bcnt, ne);
    k_scan<<<1, 1024, 0, stream>>>(bcnt, boff, bcur);
    k_partition<<<gp, PB, 0, stream>>>(src, dst, bcur, bucketed, ne);
    k_bucket_dinv<<<nb, 256, 0, stream>>>(bucketed, boff, bcnt, dinv, n);
    k_dense1<<<gn, 256, 0, stream>>>(x, W1, dinv, hs1h, n);
    k_agg1<<<nb, 256, 0, stream>>>(bucketed, boff, bcnt, hs1h, b1, W2, dinv, hs2h, n);
    k_agg2<<<nb, 256, 0, stream>>>(bucketed, boff, bcnt, hs2h, b2, dinv, out, n);
}